// Round 3
// baseline (11481.533 us; speedup 1.0000x reference)
//
#include <hip/hip_runtime.h>
#include <cstddef>

#define Vv 32000
#define Ee 1024
#define Hh 1024
#define Bb 64
#define Ss 128
#define Tt 32
#define H3 3072
#define KSPLIT 8
#define CH 16              // encoder gi chunk (timesteps)

// ---------------------------------------------------------------------------
// Chunked big GEMM: C[mlocal][n] = sum_k A(m_off+mlocal, k) * W[n][k].
// M = CH*64 rows per launch (grid.x = CH), N=3072, K=1024. All f32.
// GATHER: A(m,k) = emb[src[b*S+t]][k], m = t*64+b. else A = f32 rows.
// Tile 64x64, 256 threads, 4x4 outputs/thread, K-step 16.
// ---------------------------------------------------------------------------
template<bool GATHER>
__global__ __launch_bounds__(256)
void big_gemm(const float* __restrict__ Af,
              const float* __restrict__ emb,
              const int* __restrict__ src,
              const float* __restrict__ W,
              float* __restrict__ C, int m_off)
{
  __shared__ __align__(16) float As[16][64];
  __shared__ __align__(16) float Bs[16][64];
  const int tid = threadIdx.x;
  const int m0 = blockIdx.x * 64;          // local row base within chunk
  const int n0 = blockIdx.y * 64;
  const int lm = tid >> 2;                 // 0..63
  const int lk = (tid & 3) << 2;           // 0,4,8,12

  const float* arow;
  if (GATHER) {
    int m = m_off + m0 + lm;               // global row: t*64+b
    int b = m & (Bb - 1), t = m >> 6;
    arow = emb + (size_t)src[b * Ss + t] * Ee;
  } else {
    arow = Af + (size_t)(m_off + m0 + lm) * 1024;
  }
  const float* wrow = W + (size_t)(n0 + lm) * 1024;

  float acc[4][4];
  #pragma unroll
  for (int i = 0; i < 4; ++i)
    #pragma unroll
    for (int j = 0; j < 4; ++j) acc[i][j] = 0.f;

  const int tm = (tid >> 4) << 2;
  const int tn = (tid & 15) << 2;

  for (int k0 = 0; k0 < 1024; k0 += 16) {
    float4 a = *(const float4*)(arow + k0 + lk);
    As[lk+0][lm] = a.x; As[lk+1][lm] = a.y;
    As[lk+2][lm] = a.z; As[lk+3][lm] = a.w;
    float4 w = *(const float4*)(wrow + k0 + lk);
    Bs[lk+0][lm] = w.x; Bs[lk+1][lm] = w.y;
    Bs[lk+2][lm] = w.z; Bs[lk+3][lm] = w.w;
    __syncthreads();
    #pragma unroll
    for (int kk = 0; kk < 16; ++kk) {
      const float4 a = *(const float4*)&As[kk][tm];
      const float4 b = *(const float4*)&Bs[kk][tn];
      acc[0][0] += a.x*b.x; acc[0][1] += a.x*b.y; acc[0][2] += a.x*b.z; acc[0][3] += a.x*b.w;
      acc[1][0] += a.y*b.x; acc[1][1] += a.y*b.y; acc[1][2] += a.y*b.z; acc[1][3] += a.y*b.w;
      acc[2][0] += a.z*b.x; acc[2][1] += a.z*b.y; acc[2][2] += a.z*b.z; acc[2][3] += a.z*b.w;
      acc[3][0] += a.w*b.x; acc[3][1] += a.w*b.y; acc[3][2] += a.w*b.z; acc[3][3] += a.w*b.w;
    }
    __syncthreads();
  }
  #pragma unroll
  for (int i = 0; i < 4; ++i) {
    float4 v; v.x = acc[i][0]; v.y = acc[i][1]; v.z = acc[i][2]; v.w = acc[i][3];
    *(float4*)(C + (size_t)(m0 + tm + i) * H3 + n0 + tn) = v;
  }
}

// ---------------------------------------------------------------------------
// Small GEMM, M=64, N=3072, split-K (grid.y = KSPLIT, chunk 128), dual slot
// via grid.z. Slot0 may gather f32 emb rows (decoder layer-0 gi).
// parts layout: [KSPLIT][64][3072]
// ---------------------------------------------------------------------------
template<bool S0_GATHER>
__global__ __launch_bounds__(256)
void small_gemm(const float* __restrict__ A0, const float* __restrict__ gemb,
                const int* __restrict__ rows0,
                const float* __restrict__ W0, float* __restrict__ P0,
                const float* __restrict__ A1, const float* __restrict__ W1,
                float* __restrict__ P1)
{
  __shared__ __align__(16) float As[16][64];
  __shared__ __align__(16) float Bs[16][64];
  const int tid = threadIdx.x;
  const int n0 = blockIdx.x * 64;
  const int kbase = blockIdx.y * 128;
  const int slot = blockIdx.z;
  const float* W = (slot == 0) ? W0 : W1;
  float* dst = ((slot == 0) ? P0 : P1) + (size_t)blockIdx.y * (64 * H3);

  const int lm = tid >> 2;
  const int lk = (tid & 3) << 2;

  const float* arow;
  if (S0_GATHER && (slot == 0)) {
    arow = gemb + (size_t)rows0[lm] * Ee;
  } else {
    const float* Af = (slot == 0) ? A0 : A1;
    arow = Af + (size_t)lm * 1024;
  }
  const float* wrow = W + (size_t)(n0 + lm) * 1024;

  float acc[4][4];
  #pragma unroll
  for (int i = 0; i < 4; ++i)
    #pragma unroll
    for (int j = 0; j < 4; ++j) acc[i][j] = 0.f;

  const int tm = (tid >> 4) << 2;
  const int tn = (tid & 15) << 2;

  for (int k0 = kbase; k0 < kbase + 128; k0 += 16) {
    float4 a = *(const float4*)(arow + k0 + lk);
    As[lk+0][lm] = a.x; As[lk+1][lm] = a.y;
    As[lk+2][lm] = a.z; As[lk+3][lm] = a.w;
    float4 w = *(const float4*)(wrow + k0 + lk);
    Bs[lk+0][lm] = w.x; Bs[lk+1][lm] = w.y;
    Bs[lk+2][lm] = w.z; Bs[lk+3][lm] = w.w;
    __syncthreads();
    #pragma unroll
    for (int kk = 0; kk < 16; ++kk) {
      const float4 a = *(const float4*)&As[kk][tm];
      const float4 b = *(const float4*)&Bs[kk][tn];
      acc[0][0] += a.x*b.x; acc[0][1] += a.x*b.y; acc[0][2] += a.x*b.z; acc[0][3] += a.x*b.w;
      acc[1][0] += a.y*b.x; acc[1][1] += a.y*b.y; acc[1][2] += a.y*b.z; acc[1][3] += a.y*b.w;
      acc[2][0] += a.z*b.x; acc[2][1] += a.z*b.y; acc[2][2] += a.z*b.z; acc[2][3] += a.z*b.w;
      acc[3][0] += a.w*b.x; acc[3][1] += a.w*b.y; acc[3][2] += a.w*b.z; acc[3][3] += a.w*b.w;
    }
    __syncthreads();
  }
  #pragma unroll
  for (int i = 0; i < 4; ++i) {
    float4 v; v.x = acc[i][0]; v.y = acc[i][1]; v.z = acc[i][2]; v.w = acc[i][3];
    *(float4*)(dst + (size_t)(tm + i) * H3 + n0 + tn) = v;
  }
}

// ---------------------------------------------------------------------------
// GRU gate combine: sums split-K partials, adds biases, applies activations,
// optional padding mask, writes h (in place) and optional h_all slice.
// ---------------------------------------------------------------------------
__global__ __launch_bounds__(256)
void gru_gates(const float* __restrict__ gi, int ngi,
               const float* __restrict__ gh, int ngh,
               const float* __restrict__ bih, const float* __restrict__ bhh,
               float* __restrict__ h, float* __restrict__ hsave,
               const int* __restrict__ src_len, int t, int use_mask)
{
  int idx = blockIdx.x * 256 + threadIdx.x;   // < 65536
  int b = idx >> 10, j = idx & 1023;
  float sir = 0.f, siz = 0.f, sin_ = 0.f;
  for (int p = 0; p < ngi; ++p) {
    const float* g = gi + (size_t)p * (64 * H3) + (size_t)b * H3 + j;
    sir += g[0]; siz += g[1024]; sin_ += g[2048];
  }
  float shr = 0.f, shz = 0.f, shn = 0.f;
  for (int p = 0; p < ngh; ++p) {
    const float* g = gh + (size_t)p * (64 * H3) + (size_t)b * H3 + j;
    shr += g[0]; shz += g[1024]; shn += g[2048];
  }
  float r = 1.f / (1.f + expf(-(sir + bih[j]        + shr + bhh[j])));
  float z = 1.f / (1.f + expf(-(siz + bih[j + 1024] + shz + bhh[j + 1024])));
  float n = tanhf(sin_ + bih[j + 2048] + r * (shn + bhh[j + 2048]));
  float hp = h[idx];
  float hn = (1.f - z) * n + z * hp;
  if (use_mask && t >= src_len[b]) hn = hp;
  h[idx] = hn;
  if (hsave) hsave[idx] = hn;
}

// ---------------------------------------------------------------------------
// fc GEMM: out[b][t][n] = h[b]·fc_W[n] + fc_b[n].  M=64, N=32000, K=1024.
// Writes f32 logits directly into the output tensor slice for timestep t.
// ---------------------------------------------------------------------------
__global__ __launch_bounds__(256)
void fc_gemm(const float* __restrict__ A, const float* __restrict__ W,
             const float* __restrict__ bias,
             float* __restrict__ out, int t)
{
  __shared__ __align__(16) float As[16][64];
  __shared__ __align__(16) float Bs[16][64];
  const int tid = threadIdx.x;
  const int n0 = blockIdx.x * 64;
  const int lm = tid >> 2;
  const int lk = (tid & 3) << 2;
  const float* arow = A + (size_t)lm * 1024;
  const float* wrow = W + (size_t)(n0 + lm) * 1024;

  float acc[4][4];
  #pragma unroll
  for (int i = 0; i < 4; ++i)
    #pragma unroll
    for (int j = 0; j < 4; ++j) acc[i][j] = 0.f;

  const int tm = (tid >> 4) << 2;
  const int tn = (tid & 15) << 2;

  for (int k0 = 0; k0 < 1024; k0 += 16) {
    float4 a = *(const float4*)(arow + k0 + lk);
    As[lk+0][lm] = a.x; As[lk+1][lm] = a.y;
    As[lk+2][lm] = a.z; As[lk+3][lm] = a.w;
    float4 w = *(const float4*)(wrow + k0 + lk);
    Bs[lk+0][lm] = w.x; Bs[lk+1][lm] = w.y;
    Bs[lk+2][lm] = w.z; Bs[lk+3][lm] = w.w;
    __syncthreads();
    #pragma unroll
    for (int kk = 0; kk < 16; ++kk) {
      const float4 a = *(const float4*)&As[kk][tm];
      const float4 b = *(const float4*)&Bs[kk][tn];
      acc[0][0] += a.x*b.x; acc[0][1] += a.x*b.y; acc[0][2] += a.x*b.z; acc[0][3] += a.x*b.w;
      acc[1][0] += a.y*b.x; acc[1][1] += a.y*b.y; acc[1][2] += a.y*b.z; acc[1][3] += a.y*b.w;
      acc[2][0] += a.z*b.x; acc[2][1] += a.z*b.y; acc[2][2] += a.z*b.z; acc[2][3] += a.z*b.w;
      acc[3][0] += a.w*b.x; acc[3][1] += a.w*b.y; acc[3][2] += a.w*b.z; acc[3][3] += a.w*b.w;
    }
    __syncthreads();
  }
  #pragma unroll
  for (int i = 0; i < 4; ++i) {
    int m = tm + i;
    float4 v;
    v.x = acc[i][0] + bias[n0 + tn + 0];
    v.y = acc[i][1] + bias[n0 + tn + 1];
    v.z = acc[i][2] + bias[n0 + tn + 2];
    v.w = acc[i][3] + bias[n0 + tn + 3];
    *(float4*)(out + (size_t)m * Tt * Vv + (size_t)t * Vv + n0 + tn) = v;
  }
}

// ---------------------------------------------------------------------------
// argmax over V per batch row (reading out[:,t,:]); first-index tie-break.
// ---------------------------------------------------------------------------
__global__ __launch_bounds__(256)
void argmax_k(const float* __restrict__ out, int t, int* __restrict__ tok)
{
  __shared__ float sv[256];
  __shared__ int   si[256];
  const int b = blockIdx.x;
  const int tid = threadIdx.x;
  const float* logits = out + (size_t)b * Tt * Vv + (size_t)t * Vv;
  float best = -3.4e38f; int bi = 0;
  for (int j = tid; j < Vv; j += 256) {
    float v = logits[j];
    if (v > best) { best = v; bi = j; }
  }
  sv[tid] = best; si[tid] = bi;
  __syncthreads();
  for (int s = 128; s > 0; s >>= 1) {
    if (tid < s) {
      if (sv[tid + s] > sv[tid] || (sv[tid + s] == sv[tid] && si[tid + s] < si[tid])) {
        sv[tid] = sv[tid + s]; si[tid] = si[tid + s];
      }
    }
    __syncthreads();
  }
  if (tid == 0) tok[b] = si[0];
}

__global__ void zero_f32(float* __restrict__ p, int n)
{
  int i = blockIdx.x * 256 + threadIdx.x;
  if (i < n) p[i] = 0.f;
}

__global__ void zero_first(float* __restrict__ out)
{
  int i = blockIdx.x * 256 + threadIdx.x;   // over B*V
  if (i < Bb * Vv) {
    int b = i / Vv, v = i - b * Vv;
    out[(size_t)b * Tt * Vv + v] = 0.f;
  }
}

__global__ void tok_init(int* __restrict__ tok, const int* __restrict__ trg)
{
  int i = threadIdx.x;
  if (i < Bb) tok[i] = trg[i * Tt];
}

// ---------------------------------------------------------------------------

extern "C" void kernel_launch(void* const* d_in, const int* in_sizes, int n_in,
                              void* d_out, int out_size, void* d_ws, size_t ws_size,
                              hipStream_t stream)
{
  const int*   src     = (const int*)d_in[0];
  const int*   src_len = (const int*)d_in[1];
  const int*   trg     = (const int*)d_in[2];
  const float* emb     = (const float*)d_in[3];
  const float* enc_Wih = (const float*)d_in[4];
  const float* enc_Whh = (const float*)d_in[5];
  const float* enc_bih = (const float*)d_in[6];
  const float* enc_bhh = (const float*)d_in[7];
  const float* dec_Wih = (const float*)d_in[8];
  const float* dec_Whh = (const float*)d_in[9];
  const float* dec_bih = (const float*)d_in[10];
  const float* dec_bhh = (const float*)d_in[11];
  const float* fc_W    = (const float*)d_in[12];
  const float* fc_b    = (const float*)d_in[13];
  float* outp = (float*)d_out;

  // ---- workspace layout (floats), total ≈ 59 MB ----
  float* ws = (float*)d_ws;
  float* parts0  = ws;                                        // KSPLIT*B*3H
  float* parts1  = parts0 + (size_t)KSPLIT * Bb * H3;         // KSPLIT*B*3H
  float* h_state = parts1 + (size_t)KSPLIT * Bb * H3;         // 2*B*H
  int*   tok     = (int*)(h_state + 2 * Bb * Hh);             // 64 ints
  float* gi_ch   = (float*)(tok + 64);                        // CH*B*3H
  float* h_all   = gi_ch + (size_t)CH * Bb * H3;              // S*B*H

  const size_t Wl = (size_t)H3 * Hh;   // per-layer weight stride
  float* h0 = h_state;
  float* h1 = h_state + Bb * Hh;

  // ---- encoder ----
  zero_f32<<<(2 * Bb * Hh + 255) / 256, 256, 0, stream>>>(h_state, 2 * Bb * Hh);

  // layer 0: gi in chunks of CH timesteps, then CH sequential steps
  for (int c = 0; c < Ss; c += CH) {
    big_gemm<true><<<dim3(CH, 48), 256, 0, stream>>>(nullptr, emb, src, enc_Wih,
                                                     gi_ch, c * Bb);
    for (int t = c; t < c + CH; ++t) {
      small_gemm<false><<<dim3(48, KSPLIT, 1), 256, 0, stream>>>(
          h0, nullptr, nullptr, enc_Whh, parts1, nullptr, nullptr, nullptr);
      gru_gates<<<256, 256, 0, stream>>>(gi_ch + (size_t)(t - c) * Bb * H3, 1,
                                         parts1, KSPLIT, enc_bih, enc_bhh, h0,
                                         h_all + (size_t)t * Bb * Hh, src_len, t, 1);
    }
  }
  // layer 1: gi from h_all in chunks
  for (int c = 0; c < Ss; c += CH) {
    big_gemm<false><<<dim3(CH, 48), 256, 0, stream>>>(h_all, nullptr, nullptr,
                                                      enc_Wih + Wl, gi_ch, c * Bb);
    for (int t = c; t < c + CH; ++t) {
      small_gemm<false><<<dim3(48, KSPLIT, 1), 256, 0, stream>>>(
          h1, nullptr, nullptr, enc_Whh + Wl, parts1, nullptr, nullptr, nullptr);
      gru_gates<<<256, 256, 0, stream>>>(gi_ch + (size_t)(t - c) * Bb * H3, 1,
                                         parts1, KSPLIT, enc_bih + H3, enc_bhh + H3, h1,
                                         nullptr, src_len, t, 1);
    }
  }

  // ---- decoder ----
  zero_first<<<(Bb * Vv + 255) / 256, 256, 0, stream>>>(outp);
  tok_init<<<1, 64, 0, stream>>>(tok, trg);

  for (int t = 1; t < Tt; ++t) {
    small_gemm<true><<<dim3(48, KSPLIT, 2), 256, 0, stream>>>(
        nullptr, emb, tok, dec_Wih, parts0, h0, dec_Whh, parts1);
    gru_gates<<<256, 256, 0, stream>>>(parts0, KSPLIT, parts1, KSPLIT,
                                       dec_bih, dec_bhh, h0, nullptr, nullptr, 0, 0);
    small_gemm<false><<<dim3(48, KSPLIT, 2), 256, 0, stream>>>(
        h0, nullptr, nullptr, dec_Wih + Wl, parts0, h1, dec_Whh + Wl, parts1);
    gru_gates<<<256, 256, 0, stream>>>(parts0, KSPLIT, parts1, KSPLIT,
                                       dec_bih + H3, dec_bhh + H3, h1, nullptr, nullptr, 0, 0);
    fc_gemm<<<dim3(Vv / 64), 256, 0, stream>>>(h1, fc_W, fc_b, outp, t);
    argmax_k<<<64, 256, 0, stream>>>(outp, t, tok);
  }
}